// Round 1
// baseline (146.013 us; speedup 1.0000x reference)
//
#include <hip/hip_runtime.h>

#define N_DIM 12
#define EPS_V 1e-8f
#define FSTRIDE 132      // padded row stride (floats) for filter/tmp rows: 132*4B = 33*16B
#define CHUNK 64

// out[b,c,m,n] = gamma * sum_h Fy[b,m,h] * sum_w img[b,c,h,w] * Fx[b,n,w]
__global__ __launch_bounds__(256) void glimpse_kernel(
    const float* __restrict__ vec,   // (4096, 3)
    const float* __restrict__ img,   // (4096, 2, 128, 128)
    float* __restrict__ out)         // (4096, 2, 12, 12)
{
    const int bc = blockIdx.x;       // 0..8191
    const int b  = bc >> 1;
    const int t  = threadIdx.x;

    __shared__ __align__(16) float sF[24 * FSTRIDE];   // rows 0..11: Fx, 12..23: Fy (gamma folded)
    __shared__ __align__(16) float sTmp[12 * FSTRIDE]; // sTmp[n][h]
    __shared__ __align__(16) float sImg[CHUNK * 128];  // XOR-swizzled 16B slots
    __shared__ float sInv[24];

    // ---------- phase 0: filters ----------
    const float gx_ = vec[b * 3 + 0];
    const float gy_ = vec[b * 3 + 1];
    const float ld  = vec[b * 3 + 2];
    const float delta = 4.0f * (ld + 1.0f);
    const float gx = 64.0f * (gx_ + 1.0f);
    const float gy = 64.0f * (gy_ + 1.0f);

    #pragma unroll
    for (int k = 0; k < 6; ++k) {
        int e = t + k * 256;             // 0..1535
        int n = e >> 7;
        int a = e & 127;
        float mu_off = ((float)n - 6.5f) * delta;
        float dx = (float)a - (gx + mu_off);
        float dy = (float)a - (gy + mu_off);
        sF[n * FSTRIDE + a]        = __expf(-dx * dx * 0.25f);
        sF[(12 + n) * FSTRIDE + a] = __expf(-dy * dy * 0.25f);
    }
    __syncthreads();

    if (t < 24) {
        const float4* row = reinterpret_cast<const float4*>(&sF[t * FSTRIDE]);
        float s = 0.f;
        #pragma unroll 8
        for (int j = 0; j < 32; ++j) { float4 v = row[j]; s += v.x + v.y + v.z + v.w; }
        float inv = 1.0f / fmaxf(s, EPS_V);
        if (t >= 12) inv *= 4.0f;        // fold gamma into Fy
        sInv[t] = inv;
    }
    __syncthreads();

    #pragma unroll
    for (int k = 0; k < 6; ++k) {
        int e = t + k * 256;
        int n = e >> 7;
        int a = e & 127;
        sF[n * FSTRIDE + a]        *= sInv[n];
        sF[(12 + n) * FSTRIDE + a] *= sInv[12 + n];
    }
    __syncthreads();

    // ---------- phase 1: tmp[n][h] = sum_w img[h,w] * Fx[n,w] ----------
    const float4* gimg = reinterpret_cast<const float4*>(img) + (size_t)bc * 4096; // 128*128/4
    float4* sImg4 = reinterpret_cast<float4*>(sImg);

    const int r  = t & 63;        // row within chunk (lane id)
    const int g  = t >> 6;        // wave id = n-group (wave-uniform)
    const int n0 = 3 * g;

    const float4* fx0 = reinterpret_cast<const float4*>(&sF[(n0 + 0) * FSTRIDE]);
    const float4* fx1 = reinterpret_cast<const float4*>(&sF[(n0 + 1) * FSTRIDE]);
    const float4* fx2 = reinterpret_cast<const float4*>(&sF[(n0 + 2) * FSTRIDE]);

    for (int chunk = 0; chunk < 2; ++chunk) {
        // stage 64 rows (32KB), coalesced global float4, XOR-swizzled LDS slots
        #pragma unroll
        for (int i = 0; i < 8; ++i) {
            int idx = i * 256 + t;            // float4 index within chunk, 0..2047
            int rr  = idx >> 5;               // row 0..63
            int c4  = idx & 31;               // 16B column
            float4 v = gimg[chunk * 2048 + idx];
            sImg4[rr * 32 + (c4 ^ (rr & 31))] = v;
        }
        __syncthreads();

        float acc0 = 0.f, acc1 = 0.f, acc2 = 0.f;
        #pragma unroll 8
        for (int w4 = 0; w4 < 32; ++w4) {
            float4 iv = sImg4[r * 32 + (w4 ^ (r & 31))];
            float4 a0 = fx0[w4];
            float4 a1 = fx1[w4];
            float4 a2 = fx2[w4];
            acc0 += iv.x * a0.x + iv.y * a0.y + iv.z * a0.z + iv.w * a0.w;
            acc1 += iv.x * a1.x + iv.y * a1.y + iv.z * a1.z + iv.w * a1.w;
            acc2 += iv.x * a2.x + iv.y * a2.y + iv.z * a2.z + iv.w * a2.w;
        }
        int h = chunk * CHUNK + r;
        sTmp[(n0 + 0) * FSTRIDE + h] = acc0;
        sTmp[(n0 + 1) * FSTRIDE + h] = acc1;
        sTmp[(n0 + 2) * FSTRIDE + h] = acc2;
        __syncthreads();
    }

    // ---------- phase 2: out[m][n] = sum_h Fy'[m,h] * tmp[n,h] ----------
    if (t < 144) {
        int m = t / 12;
        int n = t % 12;
        const float4* fy = reinterpret_cast<const float4*>(&sF[(12 + m) * FSTRIDE]);
        const float4* tp = reinterpret_cast<const float4*>(&sTmp[n * FSTRIDE]);
        float acc = 0.f;
        #pragma unroll 8
        for (int h4 = 0; h4 < 32; ++h4) {
            float4 a = fy[h4];
            float4 v = tp[h4];
            acc += a.x * v.x + a.y * v.y + a.z * v.z + a.w * v.w;
        }
        out[bc * 144 + t] = acc;
    }
}

extern "C" void kernel_launch(void* const* d_in, const int* in_sizes, int n_in,
                              void* d_out, int out_size, void* d_ws, size_t ws_size,
                              hipStream_t stream) {
    const float* vec = (const float*)d_in[0];  // (4096,3) f32
    const float* img = (const float*)d_in[1];  // (4096,2,128,128) f32
    float* out = (float*)d_out;                // (4096,2,12,12) f32
    (void)in_sizes; (void)n_in; (void)out_size; (void)d_ws; (void)ws_size;

    glimpse_kernel<<<8192, 256, 0, stream>>>(vec, img, out);
}

// Round 2
// 102.312 us; speedup vs baseline: 1.4271x; 1.4271x over previous
//
#include <hip/hip_runtime.h>

typedef _Float16 half2_t __attribute__((ext_vector_type(2)));
typedef _Float16 half8_t __attribute__((ext_vector_type(8)));

#define FS 136           // f16 row stride: 136 halfs = 272 B = 17 x 16B slots (bank-rotating)
#define EPS_V 1e-8f

__device__ __forceinline__ float dot2f(half2_t a, half2_t b, float c) {
#if __has_builtin(__builtin_amdgcn_fdot2)
    return __builtin_amdgcn_fdot2(a, b, c, false);
#else
    return c + (float)a[0] * (float)b[0] + (float)a[1] * (float)b[1];
#endif
}

__device__ __forceinline__ float dot8(half8_t a, half8_t b, float c) {
    c = dot2f(__builtin_shufflevector(a, a, 0, 1), __builtin_shufflevector(b, b, 0, 1), c);
    c = dot2f(__builtin_shufflevector(a, a, 2, 3), __builtin_shufflevector(b, b, 2, 3), c);
    c = dot2f(__builtin_shufflevector(a, a, 4, 5), __builtin_shufflevector(b, b, 4, 5), c);
    c = dot2f(__builtin_shufflevector(a, a, 6, 7), __builtin_shufflevector(b, b, 6, 7), c);
    return c;
}

// out[b,c,m,n] = gamma * sum_h Fy[m,h] * sum_w img[h,w] * Fx[n,w]
__global__ __launch_bounds__(256) void glimpse_kernel(
    const float* __restrict__ vec,   // (4096, 3)
    const float* __restrict__ img,   // (4096, 2, 128, 128)
    float* __restrict__ out)         // (4096, 2, 12, 12)
{
    const int bc = blockIdx.x;
    const int b  = bc >> 1;
    const int t  = threadIdx.x;

    __shared__ __align__(16) _Float16 sImg[128 * FS];  // f16 image, 34816 B
    __shared__ __align__(16) _Float16 sFx[12 * FS];    // normalized Fx, f16
    __shared__ __align__(16) _Float16 sFy[12 * FS];    // normalized Fy * gamma, f16
    __shared__ __align__(16) _Float16 sTmp[12 * FS];   // tmp[n][h], f16

    const float gx_ = vec[b * 3 + 0];
    const float gy_ = vec[b * 3 + 1];
    const float ld  = vec[b * 3 + 2];
    const float delta = 4.0f * (ld + 1.0f);
    const float gx = 64.0f * (gx_ + 1.0f);
    const float gy = 64.0f * (gy_ + 1.0f);

    // ---------- phase 0: filters (192 threads; 24 rows x 8 lanes x 16 w) ----------
    if (t < 192) {
        const int row24 = t >> 3;        // 0..23
        const int q     = t & 7;         // 16-w segment
        const bool isFy = row24 >= 12;
        const int  nm   = isFy ? row24 - 12 : row24;
        const float mu  = (isFy ? gy : gx) + ((float)nm - 6.5f) * delta;
        const float a0f = (float)(16 * q);

        float e[16];
        float s = 0.f;
        #pragma unroll
        for (int j = 0; j < 16; ++j) {
            float d = (a0f + (float)j) - mu;
            e[j] = __expf(-d * d * 0.25f);
            s += e[j];
        }
        // reduce over the 8-lane group (lanes aligned: q = lane&7)
        s += __shfl_xor(s, 1);
        s += __shfl_xor(s, 2);
        s += __shfl_xor(s, 4);
        float inv = 1.0f / fmaxf(s, EPS_V);
        if (isFy) inv *= 4.0f;           // fold gamma

        _Float16* dst = (isFy ? sFy : sFx) + nm * FS + 16 * q;
        half8_t h0, h1;
        #pragma unroll
        for (int j = 0; j < 8; ++j) h0[j] = (_Float16)(e[j] * inv);
        #pragma unroll
        for (int j = 0; j < 8; ++j) h1[j] = (_Float16)(e[8 + j] * inv);
        *reinterpret_cast<half8_t*>(dst)     = h0;
        *reinterpret_cast<half8_t*>(dst + 8) = h1;
    }

    // ---------- stage img f32 -> f16 LDS (all 256 threads) ----------
    const float4* gimg = reinterpret_cast<const float4*>(img) + (size_t)bc * 4096;
    #pragma unroll
    for (int i = 0; i < 8; ++i) {
        int j  = i * 256 + t;            // 16B f16 slot, 0..2047
        int rr = j >> 4;                 // row
        int cc = j & 15;                 // slot within row
        float4 fa = gimg[2 * j];
        float4 fb = gimg[2 * j + 1];
        half8_t h;
        h[0] = (_Float16)fa.x; h[1] = (_Float16)fa.y;
        h[2] = (_Float16)fa.z; h[3] = (_Float16)fa.w;
        h[4] = (_Float16)fb.x; h[5] = (_Float16)fb.y;
        h[6] = (_Float16)fb.z; h[7] = (_Float16)fb.w;
        *reinterpret_cast<half8_t*>(&sImg[rr * FS + cc * 8]) = h;
    }
    __syncthreads();

    // ---------- phase 1: tmp[n][h] = sum_w img[h,w] * Fx[n,w] ----------
    {
        const int l  = t & 63;
        const int g  = t >> 6;           // wave id (uniform)
        const int n0 = 3 * g;

        const _Float16* im0 = sImg + l * FS;
        const _Float16* im1 = sImg + (l + 64) * FS;
        const _Float16* f0p = sFx + (n0 + 0) * FS;
        const _Float16* f1p = sFx + (n0 + 1) * FS;
        const _Float16* f2p = sFx + (n0 + 2) * FS;

        float a00 = 0.f, a01 = 0.f, a02 = 0.f;
        float a10 = 0.f, a11 = 0.f, a12 = 0.f;
        #pragma unroll
        for (int c = 0; c < 16; ++c) {
            half8_t i0 = *reinterpret_cast<const half8_t*>(im0 + c * 8);
            half8_t i1 = *reinterpret_cast<const half8_t*>(im1 + c * 8);
            half8_t f0 = *reinterpret_cast<const half8_t*>(f0p + c * 8);
            half8_t f1 = *reinterpret_cast<const half8_t*>(f1p + c * 8);
            half8_t f2 = *reinterpret_cast<const half8_t*>(f2p + c * 8);
            a00 = dot8(i0, f0, a00);
            a01 = dot8(i0, f1, a01);
            a02 = dot8(i0, f2, a02);
            a10 = dot8(i1, f0, a10);
            a11 = dot8(i1, f1, a11);
            a12 = dot8(i1, f2, a12);
        }
        sTmp[(n0 + 0) * FS + l]      = (_Float16)a00;
        sTmp[(n0 + 1) * FS + l]      = (_Float16)a01;
        sTmp[(n0 + 2) * FS + l]      = (_Float16)a02;
        sTmp[(n0 + 0) * FS + l + 64] = (_Float16)a10;
        sTmp[(n0 + 1) * FS + l + 64] = (_Float16)a11;
        sTmp[(n0 + 2) * FS + l + 64] = (_Float16)a12;
    }
    __syncthreads();

    // ---------- phase 2: out[m][n] = sum_h Fy'[m,h] * tmp[n,h] ----------
    if (t < 144) {
        const int m = t / 12;
        const int n = t % 12;
        const _Float16* fyp = sFy + m * FS;
        const _Float16* tpp = sTmp + n * FS;
        float acc = 0.f;
        #pragma unroll
        for (int c = 0; c < 16; ++c) {
            half8_t fy = *reinterpret_cast<const half8_t*>(fyp + c * 8);
            half8_t tp = *reinterpret_cast<const half8_t*>(tpp + c * 8);
            acc = dot8(fy, tp, acc);
        }
        out[bc * 144 + t] = acc;
    }
}

extern "C" void kernel_launch(void* const* d_in, const int* in_sizes, int n_in,
                              void* d_out, int out_size, void* d_ws, size_t ws_size,
                              hipStream_t stream) {
    const float* vec = (const float*)d_in[0];  // (4096,3) f32
    const float* img = (const float*)d_in[1];  // (4096,2,128,128) f32
    float* out = (float*)d_out;                // (4096,2,12,12) f32
    (void)in_sizes; (void)n_in; (void)out_size; (void)d_ws; (void)ws_size;

    glimpse_kernel<<<8192, 256, 0, stream>>>(vec, img, out);
}

// Round 3
// 99.582 us; speedup vs baseline: 1.4663x; 1.0274x over previous
//
#include <hip/hip_runtime.h>

typedef _Float16 half4_t __attribute__((ext_vector_type(4)));
typedef _Float16 half8_t __attribute__((ext_vector_type(8)));
typedef float    f32x4  __attribute__((ext_vector_type(4)));

#define FS 136           // f16 row stride: 136 halfs = 272 B = 17 x 16B slots
#define EPS_V 1e-8f

// out[b,c,m,n] = gamma * sum_h Fy[m,h] * sum_w img[h,w] * Fx[n,w]
__global__ __launch_bounds__(256) void glimpse_kernel(
    const float* __restrict__ vec,   // (4096, 3)
    const float* __restrict__ img,   // (4096, 2, 128, 128)
    float* __restrict__ out)         // (4096, 2, 12, 12)
{
    const int bc   = blockIdx.x;
    const int b    = bc >> 1;
    const int t    = threadIdx.x;
    const int lane = t & 63;
    const int wv   = t >> 6;
    const int fr   = lane & 15;      // fragment row/col
    const int fq   = lane >> 4;      // fragment k-quad (0..3)

    __shared__ __align__(16) _Float16 sImg[128 * FS];  // f16 image
    __shared__ __align__(16) _Float16 sFx[16 * FS];    // Fx rows 0..11, 12..15 zero
    __shared__ __align__(16) _Float16 sFy[16 * FS];    // Fy*gamma rows 0..11, 12..15 zero
    __shared__ __align__(16) _Float16 sTmp[16 * FS];   // sTmp[n][h]

    // ---------- issue all image loads first (fully coalesced dwordx4) ----------
    const float4* gimg = reinterpret_cast<const float4*>(img) + (size_t)bc * 4096;
    float4 va[8], vb[8];
    #pragma unroll
    for (int i = 0; i < 8; ++i) {
        int j = i * 256 + t;                 // 0..2047
        va[i] = gimg[j];                     // rows 0..63
        vb[i] = gimg[2048 + j];              // rows 64..127
    }

    // ---------- filters (hide under load latency) ----------
    const float gx_ = vec[b * 3 + 0];
    const float gy_ = vec[b * 3 + 1];
    const float ld  = vec[b * 3 + 2];
    const float delta = 4.0f * (ld + 1.0f);
    const float gx = 64.0f * (gx_ + 1.0f);
    const float gy = 64.0f * (gy_ + 1.0f);

    if (t < 192) {
        const int row24 = t >> 3;            // 0..23
        const int q     = t & 7;             // 16-w segment
        const bool isFy = row24 >= 12;
        const int  nm   = isFy ? row24 - 12 : row24;
        const float mu  = (isFy ? gy : gx) + ((float)nm - 6.5f) * delta;
        const float a0f = (float)(16 * q);

        float e[16];
        float s = 0.f;
        #pragma unroll
        for (int j = 0; j < 16; ++j) {
            float d = (a0f + (float)j) - mu;
            e[j] = __expf(-d * d * 0.25f);
            s += e[j];
        }
        s += __shfl_xor(s, 1);
        s += __shfl_xor(s, 2);
        s += __shfl_xor(s, 4);
        float inv = 1.0f / fmaxf(s, EPS_V);
        if (isFy) inv *= 4.0f;               // fold gamma into Fy

        _Float16* dst = (isFy ? sFy : sFx) + nm * FS + 16 * q;
        half8_t h0, h1;
        #pragma unroll
        for (int j = 0; j < 8; ++j) h0[j] = (_Float16)(e[j] * inv);
        #pragma unroll
        for (int j = 0; j < 8; ++j) h1[j] = (_Float16)(e[8 + j] * inv);
        *reinterpret_cast<half8_t*>(dst)     = h0;
        *reinterpret_cast<half8_t*>(dst + 8) = h1;
    } else {
        // zero pad rows 12..15 of sFx and sFy (4*FS = 544 halfs = 68 slots each)
        int u = t - 192;                     // 0..63
        half8_t z = {};
        for (int k = u; k < 136; k += 64) {
            _Float16* base = (k < 68 ? sFx : sFy) + 12 * FS;
            int s = (k < 68) ? k : k - 68;
            *reinterpret_cast<half8_t*>(base + s * 8) = z;
        }
    }

    // ---------- cvt f32->f16 + LDS write ----------
    #pragma unroll
    for (int i = 0; i < 8; ++i) {
        int f  = 4 * (i * 256 + t);          // float index in first half
        int rr = f >> 7;
        int cl = f & 127;
        half4_t ha, hb;
        ha[0] = (_Float16)va[i].x; ha[1] = (_Float16)va[i].y;
        ha[2] = (_Float16)va[i].z; ha[3] = (_Float16)va[i].w;
        hb[0] = (_Float16)vb[i].x; hb[1] = (_Float16)vb[i].y;
        hb[2] = (_Float16)vb[i].z; hb[3] = (_Float16)vb[i].w;
        *reinterpret_cast<half4_t*>(&sImg[rr * FS + cl])        = ha;
        *reinterpret_cast<half4_t*>(&sImg[(rr + 64) * FS + cl]) = hb;
    }
    __syncthreads();

    // ---------- phase 1: tmp = img(128x128) * Fx^T -> MFMA ----------
    // B-frag (shared across M-tiles): lane holds Fx[n=fr][k = kt*32 + 8*fq + i]
    half8_t bfrag[4];
    #pragma unroll
    for (int kt = 0; kt < 4; ++kt)
        bfrag[kt] = *reinterpret_cast<const half8_t*>(&sFx[fr * FS + kt * 32 + 8 * fq]);

    f32x4 acc0 = {0.f, 0.f, 0.f, 0.f};
    f32x4 acc1 = {0.f, 0.f, 0.f, 0.f};
    const int m0 = wv * 32;                  // this wave's 32 rows (2 M-tiles)
    #pragma unroll
    for (int kt = 0; kt < 4; ++kt) {
        half8_t a0 = *reinterpret_cast<const half8_t*>(&sImg[(m0 + fr) * FS      + kt * 32 + 8 * fq]);
        half8_t a1 = *reinterpret_cast<const half8_t*>(&sImg[(m0 + 16 + fr) * FS + kt * 32 + 8 * fq]);
        acc0 = __builtin_amdgcn_mfma_f32_16x16x32_f16(a0, bfrag[kt], acc0, 0, 0, 0);
        acc1 = __builtin_amdgcn_mfma_f32_16x16x32_f16(a1, bfrag[kt], acc1, 0, 0, 0);
    }

    // D layout: lane holds tmp[h = mtile*16 + fq*4 + r][n = fr]; store n-major
    {
        half4_t d0, d1;
        #pragma unroll
        for (int r = 0; r < 4; ++r) { d0[r] = (_Float16)acc0[r]; d1[r] = (_Float16)acc1[r]; }
        *reinterpret_cast<half4_t*>(&sTmp[fr * FS + m0 + fq * 4])      = d0;
        *reinterpret_cast<half4_t*>(&sTmp[fr * FS + m0 + 16 + fq * 4]) = d1;
    }
    __syncthreads();

    // ---------- phase 2: out = Fy'(16x128) * tmp(128x16) -> 4 MFMA on wave 0 ----------
    if (wv == 0) {
        f32x4 acc = {0.f, 0.f, 0.f, 0.f};
        #pragma unroll
        for (int kt = 0; kt < 4; ++kt) {
            half8_t a = *reinterpret_cast<const half8_t*>(&sFy[fr * FS + kt * 32 + 8 * fq]);
            half8_t bb = *reinterpret_cast<const half8_t*>(&sTmp[fr * FS + kt * 32 + 8 * fq]);
            acc = __builtin_amdgcn_mfma_f32_16x16x32_f16(a, bb, acc, 0, 0, 0);
        }
        // C[m = fq*4 + r][n = fr]; keep m,n < 12
        if (fr < 12 && fq < 3) {
            #pragma unroll
            for (int r = 0; r < 4; ++r) {
                int m = fq * 4 + r;
                out[bc * 144 + m * 12 + fr] = acc[r];
            }
        }
    }
}

extern "C" void kernel_launch(void* const* d_in, const int* in_sizes, int n_in,
                              void* d_out, int out_size, void* d_ws, size_t ws_size,
                              hipStream_t stream) {
    const float* vec = (const float*)d_in[0];  // (4096,3) f32
    const float* img = (const float*)d_in[1];  // (4096,2,128,128) f32
    float* out = (float*)d_out;                // (4096,2,12,12) f32
    (void)in_sizes; (void)n_in; (void)out_size; (void)d_ws; (void)ws_size;

    glimpse_kernel<<<8192, 256, 0, stream>>>(vec, img, out);
}